// Round 1
// baseline (193.120 us; speedup 1.0000x reference)
//
#include <hip/hip_runtime.h>
#include <math.h>

// SO3 convolution lmax=2 — fused 2-dispatch pipeline.
//   K1) csr_kernel: ONE block (1024 thr). LDS histogram of idx_i, LDS scan ->
//       offsets/chunk_off, LDS-cursor scatter -> esorted. Zeroes done[] and the
//       out-rows of degree-0 atoms. No global memsets, no extra dispatches.
//   K2) so3_chunk_kernel: one 64-thread wave per chunk (<= CEDGE edges, one atom).
//       Stages radial rows in LDS, computes all edges' radial filters in ONE pass
//       over Wf (loads /8 vs per-edge). Builds M[9][12] per edge from sparse CG.
//       Fully-unrolled edge loop contracts against x[j].
//       Epilogue: single-chunk atom -> direct store to out;
//       multi-chunk -> slot store, __threadfence, atomicAdd(done); the LAST
//       chunk sums sibling slots (+ its own regs) and writes out.
//   Fallback (ws too small for slots): atomicAdd into zeroed out.

#define S9     9
#define MROW   12          // padded M row stride (floats)
#define NF     128
#define NRAD   20
#define CEDGE  8           // edges per chunk
#define MAXA   2048

__device__ inline float2 f2fma(float a, float2 b, float2 c) {
    return make_float2(fmaf(a, b.x, c.x), fmaf(a, b.y, c.y));
}

// ---------- K1: fused CSR build (single block, 1024 threads, A <= 2048) ----------
__global__ __launch_bounds__(1024) void csr_kernel(
    const int* __restrict__ idx_i, int E, int A,
    int* __restrict__ offsets,      // [A+1]
    int* __restrict__ chunk_off,    // [A+1]
    int* __restrict__ esorted,      // [E]
    int* __restrict__ done,         // [A]
    float* __restrict__ out)        // [A,9,128] — zero rows of deg-0 atoms
{
    __shared__ int lcnt[MAXA];
    __shared__ int lcur[MAXA];
    __shared__ int part[1024];
    const int t = threadIdx.x;

    for (int i = t; i < A; i += 1024) lcnt[i] = 0;
    __syncthreads();
    for (int e = t; e < E; e += 1024) atomicAdd(&lcnt[idx_i[e]], 1);
    __syncthreads();

    const int i0 = 2 * t, i1 = 2 * t + 1;
    const int ca = (i0 < A) ? lcnt[i0] : 0;
    const int cb = (i1 < A) ? lcnt[i1] : 0;

    // scan 1: edge offsets
    part[t] = ca + cb;
    __syncthreads();
    for (int off = 1; off < 1024; off <<= 1) {
        int v = (t >= off) ? part[t - off] : 0;
        __syncthreads();
        part[t] += v;
        __syncthreads();
    }
    int run = part[t] - (ca + cb);
    if (i0 < A) { offsets[i0] = run; lcur[i0] = run; run += ca; }
    if (i1 < A) { offsets[i1] = run; lcur[i1] = run; run += cb; }
    if (t == 1023) offsets[A] = run;
    __syncthreads();

    // scan 2: chunk offsets (ceil(deg/CEDGE))
    const int ka = (i0 < A) ? ((ca + CEDGE - 1) / CEDGE) : 0;
    const int kb = (i1 < A) ? ((cb + CEDGE - 1) / CEDGE) : 0;
    part[t] = ka + kb;
    __syncthreads();
    for (int off = 1; off < 1024; off <<= 1) {
        int v = (t >= off) ? part[t - off] : 0;
        __syncthreads();
        part[t] += v;
        __syncthreads();
    }
    int run2 = part[t] - (ka + kb);
    if (i0 < A) { chunk_off[i0] = run2; run2 += ka; }
    if (i1 < A) { chunk_off[i1] = run2; run2 += kb; }
    if (t == 1023) chunk_off[A] = run2;

    // zero completion counters + out-rows of degree-0 atoms (rare)
    const float4 z4 = make_float4(0.f, 0.f, 0.f, 0.f);
    if (i0 < A) {
        done[i0] = 0;
        if (ca == 0) {
            float4* o = (float4*)(out + (size_t)i0 * (S9 * NF));
            for (int s = 0; s < S9 * NF / 4; ++s) o[s] = z4;
        }
    }
    if (i1 < A) {
        done[i1] = 0;
        if (cb == 0) {
            float4* o = (float4*)(out + (size_t)i1 * (S9 * NF));
            for (int s = 0; s < S9 * NF / 4; ++s) o[s] = z4;
        }
    }
    __syncthreads();

    // scatter (stable order not required)
    for (int e = t; e < E; e += 1024) {
        int p = atomicAdd(&lcur[idx_i[e]], 1);
        esorted[p] = e;
    }
}

// ---------- K2: one wave per chunk, fused reduction ----------
__global__ __launch_bounds__(64) void so3_chunk_kernel(
    const float* __restrict__ x,        // [A, 9, 128]
    const float* __restrict__ radial,   // [E, 20]
    const float* __restrict__ dir,      // [E, 3]
    const float* __restrict__ cutoff,   // [E]
    const float* __restrict__ Wf,       // [20, 384]
    const float* __restrict__ bf,       // [384]
    const float* __restrict__ cg_vals,
    const int* __restrict__ idx_j,
    const int* __restrict__ cg_i1,
    const int* __restrict__ cg_i2,
    const int* __restrict__ cg_i3,
    int ncg, int A,
    const int* __restrict__ offsets,    // [A+1]
    const int* __restrict__ chunk_off,  // [A+1]
    const int* __restrict__ esorted,    // [E]
    float* __restrict__ slots,          // [nchunks, 9, 128] (or unused)
    int* __restrict__ done,             // [A]
    float* __restrict__ out,            // [A, 9, 128]
    int use_slots)
{
    const int ch = blockIdx.x;
    const int nchunks = chunk_off[A];
    if (ch >= nchunks) return;

    // binary search: atom a with chunk_off[a] <= ch < chunk_off[a+1]
    int lo = 0, hi = A;
    while (hi - lo > 1) {
        int mid = (lo + hi) >> 1;
        if (chunk_off[mid] <= ch) lo = mid; else hi = mid;
    }
    const int a = lo;
    const int c0ch = chunk_off[a];
    const int c1ch = chunk_off[a + 1];
    const int q = ch - c0ch;
    const int estart = offsets[a] + q * CEDGE;
    const int n = min(CEDGE, offsets[a + 1] - estart);

    const int t = threadIdx.x;           // f-pair index: f = 2t, 2t+1

    __shared__ __align__(16) float M[CEDGE][MROW * S9];
    __shared__ float Ysh[CEDGE][S9];
    __shared__ float radsh[CEDGE][NRAD];
    __shared__ float cutsh[CEDGE];
    __shared__ int   els[CEDGE];

    // ---- phase A: zero M, edge ids, SH, stage radial/cutoff ----
    {
        float4* Mz = (float4*)&M[0][0];
        const int tot4 = CEDGE * MROW * S9 / 4;   // 216
        for (int qq = t; qq < tot4; qq += 64) Mz[qq] = make_float4(0.f, 0.f, 0.f, 0.f);
    }
    if (t < n) {
        const int e = esorted[estart + t];
        els[t] = e;
        float dx = dir[3 * e], dy = dir[3 * e + 1], dz = dir[3 * e + 2];
        const float inv = rsqrtf(dx * dx + dy * dy + dz * dz);
        dx *= inv; dy *= inv; dz *= inv;
        const float s3c  = 1.7320508075688772f;
        const float s5c  = 2.2360679774997896f;
        const float s15c = 3.8729833462074170f;
        Ysh[t][0] = 1.0f;
        Ysh[t][1] = s3c * dy;
        Ysh[t][2] = s3c * dz;
        Ysh[t][3] = s3c * dx;
        Ysh[t][4] = s15c * dx * dy;
        Ysh[t][5] = s15c * dy * dz;
        Ysh[t][6] = 0.5f * s5c * (3.0f * dz * dz - 1.0f);
        Ysh[t][7] = s15c * dx * dz;
        Ysh[t][8] = 0.5f * s15c * (dx * dx - dy * dy);
    }
    if (t < CEDGE) cutsh[t] = (t < n) ? cutoff[esorted[estart + t]] : 0.f;
    for (int qq = t; qq < CEDGE * NRAD; qq += 64) {
        const int c = qq / NRAD;
        const int r = qq - c * NRAD;
        radsh[c][r] = (c < n) ? radial[(size_t)esorted[estart + c] * NRAD + r] : 0.f;
    }
    __syncthreads();

    // ---- phase B1: radial filters for ALL chunk edges in one Wf pass ----
    // w[c][l] = cutoff_c * (bf + sum_r rad[c][r] * Wf[r])   (this thread's 2 cols)
    const float2 b0 = ((const float2*)(bf + 0 * NF))[t];
    const float2 b1 = ((const float2*)(bf + 1 * NF))[t];
    const float2 b2 = ((const float2*)(bf + 2 * NF))[t];
    float2 w[CEDGE][3];
    #pragma unroll
    for (int c = 0; c < CEDGE; ++c) { w[c][0] = b0; w[c][1] = b1; w[c][2] = b2; }
    #pragma unroll 4
    for (int r = 0; r < NRAD; ++r) {
        const float2* wrow = (const float2*)(Wf + r * (3 * NF));
        const float2 w0 = wrow[t];
        const float2 w1 = wrow[t + 64];
        const float2 w2 = wrow[t + 128];
        #pragma unroll
        for (int c = 0; c < CEDGE; ++c) {
            const float rv = radsh[c][r];   // 0 for c >= n
            w[c][0] = f2fma(rv, w0, w[c][0]);
            w[c][1] = f2fma(rv, w1, w[c][1]);
            w[c][2] = f2fma(rv, w2, w[c][2]);
        }
    }
    #pragma unroll
    for (int c = 0; c < CEDGE; ++c) {
        const float cut = cutsh[c];
        w[c][0].x *= cut; w[c][0].y *= cut;
        w[c][1].x *= cut; w[c][1].y *= cut;
        w[c][2].x *= cut; w[c][2].y *= cut;
    }

    // ---- phase B2: build M for all n edges (8 threads per edge) ----
    {
        const int c = t >> 3;
        const int r = t & 7;
        if (c < n) {
            for (int kk = r; kk < ncg; kk += 8) {
                atomicAdd(&M[c][cg_i3[kk] * MROW + cg_i1[kk]], cg_vals[kk] * Ysh[c][cg_i2[kk]]);
            }
        }
    }
    __syncthreads();

    // ---- phase C: contract edges (fully unrolled, static w[c] indexing) ----
    float2 acc[S9];
    #pragma unroll
    for (int s = 0; s < S9; ++s) acc[s] = make_float2(0.f, 0.f);

    #pragma unroll
    for (int c = 0; c < CEDGE; ++c) {
        if (c >= n) break;
        const int e = __builtin_amdgcn_readfirstlane(els[c]);
        const int j = __builtin_amdgcn_readfirstlane(idx_j[e]);

        const float2* xp = (const float2*)(x + (size_t)j * (S9 * NF)) + t;
        float2 xj[S9];
        #pragma unroll
        for (int s = 0; s < S9; ++s) xj[s] = xp[s * 64];

        #pragma unroll
        for (int s3 = 0; s3 < S9; ++s3) {
            const float4* mr = (const float4*)&M[c][s3 * MROW];
            const float4 m0 = mr[0];
            const float4 m1 = mr[1];
            const float  m8 = M[c][s3 * MROW + 8];
            float2 tsum = make_float2(0.f, 0.f);
            tsum = f2fma(m0.x, xj[0], tsum);
            tsum = f2fma(m0.y, xj[1], tsum);
            tsum = f2fma(m0.z, xj[2], tsum);
            tsum = f2fma(m0.w, xj[3], tsum);
            tsum = f2fma(m1.x, xj[4], tsum);
            tsum = f2fma(m1.y, xj[5], tsum);
            tsum = f2fma(m1.z, xj[6], tsum);
            tsum = f2fma(m1.w, xj[7], tsum);
            tsum = f2fma(m8,   xj[8], tsum);
            const float2 wl = (s3 == 0) ? w[c][0] : ((s3 < 4) ? w[c][1] : w[c][2]);
            acc[s3].x = fmaf(wl.x, tsum.x, acc[s3].x);
            acc[s3].y = fmaf(wl.y, tsum.y, acc[s3].y);
        }
    }

    // ---- epilogue ----
    if (!use_slots) {
        float* op = out + (size_t)a * (S9 * NF) + 2 * t;
        #pragma unroll
        for (int s = 0; s < S9; ++s) {
            atomicAdd(&op[s * NF],     acc[s].x);
            atomicAdd(&op[s * NF + 1], acc[s].y);
        }
        return;
    }

    const int nch = c1ch - c0ch;
    if (nch == 1) {
        float2* op = (float2*)(out + (size_t)a * (S9 * NF)) + t;
        #pragma unroll
        for (int s = 0; s < S9; ++s) op[s * 64] = acc[s];
        return;
    }

    // multi-chunk: publish slot, then last chunk reduces
    float2* sp = (float2*)(slots + (size_t)ch * (S9 * NF)) + t;
    #pragma unroll
    for (int s = 0; s < S9; ++s) sp[s * 64] = acc[s];
    __threadfence();                              // release slot stores
    int old = 0;
    if (t == 0) old = atomicAdd(&done[a], 1);     // device-scope
    old = __shfl(old, 0);
    if (old == nch - 1) {
        __threadfence();                          // acquire sibling slots
        for (int ch2 = c0ch; ch2 < c1ch; ++ch2) {
            if (ch2 == ch) continue;
            const float2* rp = (const float2*)(slots + (size_t)ch2 * (S9 * NF)) + t;
            #pragma unroll
            for (int s = 0; s < S9; ++s) {
                float2 v = rp[s * 64];
                acc[s].x += v.x; acc[s].y += v.y;
            }
        }
        float2* op = (float2*)(out + (size_t)a * (S9 * NF)) + t;
        #pragma unroll
        for (int s = 0; s < S9; ++s) op[s * 64] = acc[s];
    }
}

extern "C" void kernel_launch(void* const* d_in, const int* in_sizes, int n_in,
                              void* d_out, int out_size, void* d_ws, size_t ws_size,
                              hipStream_t stream) {
    const float* x       = (const float*)d_in[0];
    const float* radial  = (const float*)d_in[1];
    const float* dir     = (const float*)d_in[2];
    const float* cutoff  = (const float*)d_in[3];
    const float* Wf      = (const float*)d_in[4];
    const float* bf      = (const float*)d_in[5];
    const float* cg_vals = (const float*)d_in[6];
    const int*   idx_i   = (const int*)d_in[7];
    const int*   idx_j   = (const int*)d_in[8];
    const int*   cg_i1   = (const int*)d_in[9];
    const int*   cg_i2   = (const int*)d_in[10];
    const int*   cg_i3   = (const int*)d_in[11];
    // d_in[12] = w_idx: unused (w_idx[k] == l(cg_idx_out[k]), folded into kernel)

    const int E   = in_sizes[7];
    const int ncg = in_sizes[6];
    const int A   = in_sizes[0] / (S9 * NF);

    // ws ints: offsets[A+1] | chunk_off[A+1] | done[A] | esorted[E]
    int* offsets   = (int*)d_ws;
    int* chunk_off = offsets + (A + 1);
    int* done      = chunk_off + (A + 1);
    int* esorted   = done + A;
    size_t int_bytes = (size_t)(3 * A + 2 + E) * sizeof(int);
    size_t slots_off = (int_bytes + 255) & ~(size_t)255;

    const int max_chunks = E / CEDGE + A;   // upper bound on total chunks
    size_t slots_bytes = (size_t)max_chunks * (S9 * NF) * sizeof(float);
    const int use_slots = (ws_size >= slots_off + slots_bytes) ? 1 : 0;
    float* slots = (float*)((char*)d_ws + slots_off);
    float* out   = (float*)d_out;

    if (!use_slots) {
        // atomic fallback needs zeroed output
        hipMemsetAsync(out, 0, (size_t)out_size * sizeof(float), stream);
    }

    csr_kernel<<<1, 1024, 0, stream>>>(idx_i, E, A, offsets, chunk_off, esorted, done, out);

    so3_chunk_kernel<<<max_chunks, 64, 0, stream>>>(
        x, radial, dir, cutoff, Wf, bf, cg_vals, idx_j,
        cg_i1, cg_i2, cg_i3, ncg, A, offsets, chunk_off, esorted,
        slots, done, out, use_slots);
}

// Round 2
// 125.243 us; speedup vs baseline: 1.5420x; 1.5420x over previous
//
#include <hip/hip_runtime.h>
#include <math.h>

// SO3 convolution lmax=2 — 3-dispatch pipeline, latency-lean chunk kernel.
//   K1) csr_kernel: ONE block (1024 thr). LDS histogram + scans -> offsets /
//       chunk_off / chunk_atom (chunk -> atom map, kills binary search),
//       LDS-cursor scatter -> esorted, zeroes deg-0 out rows.
//   K2) so3_chunk_kernel: one 64-thread wave per chunk (exactly CEDGE=8 edge
//       slots; tail slots are exact zeros: cut=0, rad=0, M=0, jsh=self).
//       Phase B1: radial filters for all 8 slots in ONE Wf pass -> LDS wsh.
//       Phase B2: sparse-CG M[9][12] per edge in LDS.
//       Phase C: branch-free fully-unrolled 8-edge contraction (j prefetched
//       in LDS, no break, no fences). nch==1 atoms store out directly,
//       else plain slot stores.
//   K3) so3_reduce_kernel: one wave per multi-chunk atom sums its slots.
//   Fallback (ws too small for slots): atomicAdd into zeroed out.

#define S9     9
#define MROW   12          // padded M row stride (floats)
#define NF     128
#define NRAD   20
#define CEDGE  8           // edges per chunk
#define MAXA   2048

__device__ inline float2 f2fma(float a, float2 b, float2 c) {
    return make_float2(fmaf(a, b.x, c.x), fmaf(a, b.y, c.y));
}

// ---------- K1: fused CSR build (single block, 1024 threads, A <= 2048) ----------
__global__ __launch_bounds__(1024) void csr_kernel(
    const int* __restrict__ idx_i, int E, int A, int max_chunks,
    int* __restrict__ offsets,      // [A+1]
    int* __restrict__ chunk_off,    // [A+1]
    int* __restrict__ chunk_atom,   // [max_chunks]
    int* __restrict__ esorted,      // [E]
    float* __restrict__ out)        // [A,9,128] — zero rows of deg-0 atoms
{
    __shared__ int lcnt[MAXA];
    __shared__ int lcur[MAXA];
    __shared__ int part[1024];
    __shared__ int nch_sh;
    const int t = threadIdx.x;

    for (int i = t; i < A; i += 1024) lcnt[i] = 0;
    __syncthreads();
    for (int e = t; e < E; e += 1024) atomicAdd(&lcnt[idx_i[e]], 1);
    __syncthreads();

    const int i0 = 2 * t, i1 = 2 * t + 1;
    const int ca = (i0 < A) ? lcnt[i0] : 0;
    const int cb = (i1 < A) ? lcnt[i1] : 0;

    // scan 1: edge offsets
    part[t] = ca + cb;
    __syncthreads();
    for (int off = 1; off < 1024; off <<= 1) {
        int v = (t >= off) ? part[t - off] : 0;
        __syncthreads();
        part[t] += v;
        __syncthreads();
    }
    int run = part[t] - (ca + cb);
    if (i0 < A) { offsets[i0] = run; lcur[i0] = run; run += ca; }
    if (i1 < A) { offsets[i1] = run; lcur[i1] = run; run += cb; }
    if (t == 1023) offsets[A] = run;
    __syncthreads();

    // scan 2: chunk offsets (ceil(deg/CEDGE)) + chunk->atom map
    const int ka = (i0 < A) ? ((ca + CEDGE - 1) / CEDGE) : 0;
    const int kb = (i1 < A) ? ((cb + CEDGE - 1) / CEDGE) : 0;
    part[t] = ka + kb;
    __syncthreads();
    for (int off = 1; off < 1024; off <<= 1) {
        int v = (t >= off) ? part[t - off] : 0;
        __syncthreads();
        part[t] += v;
        __syncthreads();
    }
    int run2 = part[t] - (ka + kb);
    if (i0 < A) {
        chunk_off[i0] = run2;
        for (int k = 0; k < ka; ++k) chunk_atom[run2 + k] = i0;
        run2 += ka;
    }
    if (i1 < A) {
        chunk_off[i1] = run2;
        for (int k = 0; k < kb; ++k) chunk_atom[run2 + k] = i1;
        run2 += kb;
    }
    if (t == 1023) { chunk_off[A] = run2; nch_sh = run2; }

    // zero out-rows of degree-0 atoms (rare)
    const float4 z4 = make_float4(0.f, 0.f, 0.f, 0.f);
    if (i0 < A && ca == 0) {
        float4* o = (float4*)(out + (size_t)i0 * (S9 * NF));
        for (int s = 0; s < S9 * NF / 4; ++s) o[s] = z4;
    }
    if (i1 < A && cb == 0) {
        float4* o = (float4*)(out + (size_t)i1 * (S9 * NF));
        for (int s = 0; s < S9 * NF / 4; ++s) o[s] = z4;
    }
    __syncthreads();

    // invalidate tail chunk slots (grid is max_chunks)
    for (int i = nch_sh + t; i < max_chunks; i += 1024) chunk_atom[i] = -1;

    // scatter (stable order not required)
    for (int e = t; e < E; e += 1024) {
        int p = atomicAdd(&lcur[idx_i[e]], 1);
        esorted[p] = e;
    }
}

// ---------- K2: one wave per chunk ----------
__global__ __launch_bounds__(64) void so3_chunk_kernel(
    const float* __restrict__ x,        // [A, 9, 128]
    const float* __restrict__ radial,   // [E, 20]
    const float* __restrict__ dir,      // [E, 3]
    const float* __restrict__ cutoff,   // [E]
    const float* __restrict__ Wf,       // [20, 384]
    const float* __restrict__ bf,       // [384]
    const float* __restrict__ cg_vals,
    const int* __restrict__ idx_j,
    const int* __restrict__ cg_i1,
    const int* __restrict__ cg_i2,
    const int* __restrict__ cg_i3,
    int ncg, int A,
    const int* __restrict__ offsets,    // [A+1]
    const int* __restrict__ chunk_off,  // [A+1]
    const int* __restrict__ chunk_atom, // [max_chunks]
    const int* __restrict__ esorted,    // [E]
    float* __restrict__ slots,          // [nchunks, 9, 128] (or unused)
    float* __restrict__ out,            // [A, 9, 128]
    int use_slots)
{
    const int ch = blockIdx.x;
    const int a = chunk_atom[ch];
    if (a < 0) return;

    const int c0ch = chunk_off[a];
    const int nch  = chunk_off[a + 1] - c0ch;
    const int estart = offsets[a] + (ch - c0ch) * CEDGE;
    const int n = min(CEDGE, offsets[a + 1] - estart);

    const int t = threadIdx.x;           // f-pair index: f = 2t, 2t+1

    __shared__ __align__(16) float M[CEDGE][MROW * S9];
    __shared__ float Ysh[CEDGE][S9];
    __shared__ float radsh[CEDGE][NRAD];
    __shared__ float cutsh[CEDGE];
    __shared__ float wsh[CEDGE][3][NF];
    __shared__ int   jsh[CEDGE];

    // ---- phase A: zero M, per-slot metadata, SH, stage radial ----
    {
        float4* Mz = (float4*)&M[0][0];
        const int tot4 = CEDGE * MROW * S9 / 4;   // 216
        for (int qq = t; qq < tot4; qq += 64) Mz[qq] = make_float4(0.f, 0.f, 0.f, 0.f);
    }
    if (t < CEDGE) {
        int jj = a;              // tail slots: any valid row (contribution is 0)
        float cut = 0.f;
        if (t < n) {
            const int e = esorted[estart + t];
            jj = idx_j[e];
            cut = cutoff[e];
            float dx = dir[3 * e], dy = dir[3 * e + 1], dz = dir[3 * e + 2];
            const float inv = rsqrtf(dx * dx + dy * dy + dz * dz);
            dx *= inv; dy *= inv; dz *= inv;
            const float s3c  = 1.7320508075688772f;
            const float s5c  = 2.2360679774997896f;
            const float s15c = 3.8729833462074170f;
            Ysh[t][0] = 1.0f;
            Ysh[t][1] = s3c * dy;
            Ysh[t][2] = s3c * dz;
            Ysh[t][3] = s3c * dx;
            Ysh[t][4] = s15c * dx * dy;
            Ysh[t][5] = s15c * dy * dz;
            Ysh[t][6] = 0.5f * s5c * (3.0f * dz * dz - 1.0f);
            Ysh[t][7] = s15c * dx * dz;
            Ysh[t][8] = 0.5f * s15c * (dx * dx - dy * dy);
        }
        jsh[t] = jj;
        cutsh[t] = cut;
    }
    for (int qq = t; qq < CEDGE * NRAD; qq += 64) {
        const int c = qq / NRAD;
        const int r = qq - c * NRAD;
        radsh[c][r] = (c < n) ? radial[(size_t)esorted[estart + c] * NRAD + r] : 0.f;
    }
    __syncthreads();

    // ---- phase B1: radial filters for ALL 8 slots in one Wf pass -> wsh ----
    {
        const float2 b0 = ((const float2*)(bf + 0 * NF))[t];
        const float2 b1 = ((const float2*)(bf + 1 * NF))[t];
        const float2 b2 = ((const float2*)(bf + 2 * NF))[t];
        float2 w[CEDGE][3];
        #pragma unroll
        for (int c = 0; c < CEDGE; ++c) { w[c][0] = b0; w[c][1] = b1; w[c][2] = b2; }
        #pragma unroll 4
        for (int r = 0; r < NRAD; ++r) {
            const float2* wrow = (const float2*)(Wf + r * (3 * NF));
            const float2 w0 = wrow[t];
            const float2 w1 = wrow[t + 64];
            const float2 w2 = wrow[t + 128];
            #pragma unroll
            for (int c = 0; c < CEDGE; ++c) {
                const float rv = radsh[c][r];   // 0 for c >= n
                w[c][0] = f2fma(rv, w0, w[c][0]);
                w[c][1] = f2fma(rv, w1, w[c][1]);
                w[c][2] = f2fma(rv, w2, w[c][2]);
            }
        }
        #pragma unroll
        for (int c = 0; c < CEDGE; ++c) {
            const float cut = cutsh[c];          // 0 for c >= n -> wsh row = 0
            ((float2*)&wsh[c][0][0])[t] = make_float2(w[c][0].x * cut, w[c][0].y * cut);
            ((float2*)&wsh[c][1][0])[t] = make_float2(w[c][1].x * cut, w[c][1].y * cut);
            ((float2*)&wsh[c][2][0])[t] = make_float2(w[c][2].x * cut, w[c][2].y * cut);
        }
    }

    // ---- phase B2: build M for all n edges (8 threads per edge) ----
    {
        const int c = t >> 3;
        const int r = t & 7;
        if (c < n) {
            for (int kk = r; kk < ncg; kk += 8) {
                atomicAdd(&M[c][cg_i3[kk] * MROW + cg_i1[kk]], cg_vals[kk] * Ysh[c][cg_i2[kk]]);
            }
        }
    }
    __syncthreads();

    // ---- phase C: branch-free fully-unrolled 8-edge contraction ----
    float2 acc[S9];
    #pragma unroll
    for (int s = 0; s < S9; ++s) acc[s] = make_float2(0.f, 0.f);

    #pragma unroll
    for (int c = 0; c < CEDGE; ++c) {
        const int j = __builtin_amdgcn_readfirstlane(jsh[c]);

        const float2* xp = (const float2*)(x + (size_t)j * (S9 * NF)) + t;
        float2 xj[S9];
        #pragma unroll
        for (int s = 0; s < S9; ++s) xj[s] = xp[s * 64];

        const float2* wp = (const float2*)&wsh[c][0][0] + t;
        const float2 wl0 = wp[0];
        const float2 wl1 = wp[64];
        const float2 wl2 = wp[128];

        #pragma unroll
        for (int s3 = 0; s3 < S9; ++s3) {
            const float4* mr = (const float4*)&M[c][s3 * MROW];
            const float4 m0 = mr[0];
            const float4 m1 = mr[1];
            const float  m8 = M[c][s3 * MROW + 8];
            float2 tsum = make_float2(0.f, 0.f);
            tsum = f2fma(m0.x, xj[0], tsum);
            tsum = f2fma(m0.y, xj[1], tsum);
            tsum = f2fma(m0.z, xj[2], tsum);
            tsum = f2fma(m0.w, xj[3], tsum);
            tsum = f2fma(m1.x, xj[4], tsum);
            tsum = f2fma(m1.y, xj[5], tsum);
            tsum = f2fma(m1.z, xj[6], tsum);
            tsum = f2fma(m1.w, xj[7], tsum);
            tsum = f2fma(m8,   xj[8], tsum);
            const float2 wl = (s3 == 0) ? wl0 : ((s3 < 4) ? wl1 : wl2);
            acc[s3].x = fmaf(wl.x, tsum.x, acc[s3].x);
            acc[s3].y = fmaf(wl.y, tsum.y, acc[s3].y);
        }
    }

    // ---- epilogue: plain stores only, no fences ----
    if (!use_slots) {
        float* op = out + (size_t)a * (S9 * NF) + 2 * t;
        #pragma unroll
        for (int s = 0; s < S9; ++s) {
            atomicAdd(&op[s * NF],     acc[s].x);
            atomicAdd(&op[s * NF + 1], acc[s].y);
        }
        return;
    }

    if (nch == 1) {
        float2* op = (float2*)(out + (size_t)a * (S9 * NF)) + t;
        #pragma unroll
        for (int s = 0; s < S9; ++s) op[s * 64] = acc[s];
    } else {
        float2* sp = (float2*)(slots + (size_t)ch * (S9 * NF)) + t;
        #pragma unroll
        for (int s = 0; s < S9; ++s) sp[s * 64] = acc[s];
    }
}

// ---------- K3: one wave per multi-chunk atom sums its slots ----------
__global__ __launch_bounds__(64) void so3_reduce_kernel(
    const float* __restrict__ slots, const int* __restrict__ chunk_off,
    float* __restrict__ out)
{
    const int a = blockIdx.x;
    const int t = threadIdx.x;
    const int c0 = chunk_off[a];
    const int c1 = chunk_off[a + 1];
    if (c1 - c0 < 2) return;    // deg-0 zeroed by K1; single-chunk stored by K2

    float2 acc[S9];
    #pragma unroll
    for (int s = 0; s < S9; ++s) acc[s] = make_float2(0.f, 0.f);

    for (int ch = c0; ch < c1; ++ch) {
        const float2* sp = (const float2*)(slots + (size_t)ch * (S9 * NF)) + t;
        #pragma unroll
        for (int s = 0; s < S9; ++s) {
            float2 v = sp[s * 64];
            acc[s].x += v.x; acc[s].y += v.y;
        }
    }
    float2* op = (float2*)(out + (size_t)a * (S9 * NF)) + t;
    #pragma unroll
    for (int s = 0; s < S9; ++s) op[s * 64] = acc[s];
}

extern "C" void kernel_launch(void* const* d_in, const int* in_sizes, int n_in,
                              void* d_out, int out_size, void* d_ws, size_t ws_size,
                              hipStream_t stream) {
    const float* x       = (const float*)d_in[0];
    const float* radial  = (const float*)d_in[1];
    const float* dir     = (const float*)d_in[2];
    const float* cutoff  = (const float*)d_in[3];
    const float* Wf      = (const float*)d_in[4];
    const float* bf      = (const float*)d_in[5];
    const float* cg_vals = (const float*)d_in[6];
    const int*   idx_i   = (const int*)d_in[7];
    const int*   idx_j   = (const int*)d_in[8];
    const int*   cg_i1   = (const int*)d_in[9];
    const int*   cg_i2   = (const int*)d_in[10];
    const int*   cg_i3   = (const int*)d_in[11];
    // d_in[12] = w_idx: unused (w_idx[k] == l(cg_idx_out[k]), folded into kernel)

    const int E   = in_sizes[7];
    const int ncg = in_sizes[6];
    const int A   = in_sizes[0] / (S9 * NF);

    const int max_chunks = E / CEDGE + A;   // upper bound on total chunks

    // ws ints: offsets[A+1] | chunk_off[A+1] | chunk_atom[max_chunks] | esorted[E]
    int* offsets    = (int*)d_ws;
    int* chunk_off  = offsets + (A + 1);
    int* chunk_atom = chunk_off + (A + 1);
    int* esorted    = chunk_atom + max_chunks;
    size_t int_bytes = (size_t)(2 * A + 2 + max_chunks + E) * sizeof(int);
    size_t slots_off = (int_bytes + 255) & ~(size_t)255;

    size_t slots_bytes = (size_t)max_chunks * (S9 * NF) * sizeof(float);
    const int use_slots = (ws_size >= slots_off + slots_bytes) ? 1 : 0;
    float* slots = (float*)((char*)d_ws + slots_off);
    float* out   = (float*)d_out;

    if (!use_slots) {
        // atomic fallback needs zeroed output
        hipMemsetAsync(out, 0, (size_t)out_size * sizeof(float), stream);
    }

    csr_kernel<<<1, 1024, 0, stream>>>(idx_i, E, A, max_chunks,
                                       offsets, chunk_off, chunk_atom, esorted, out);

    so3_chunk_kernel<<<max_chunks, 64, 0, stream>>>(
        x, radial, dir, cutoff, Wf, bf, cg_vals, idx_j,
        cg_i1, cg_i2, cg_i3, ncg, A, offsets, chunk_off, chunk_atom, esorted,
        slots, out, use_slots);

    if (use_slots) {
        so3_reduce_kernel<<<A, 64, 0, stream>>>(slots, chunk_off, out);
    }
}

// Round 3
// 124.452 us; speedup vs baseline: 1.5518x; 1.0064x over previous
//
#include <hip/hip_runtime.h>
#include <math.h>

// SO3 convolution lmax=2 — 3-dispatch pipeline, TLP-heavy chunk kernel.
//   K1) csr_kernel: ONE block (1024 thr). LDS histogram; ONE packed 64-bit
//       shfl-wave scan produces edge offsets (low32) and chunk offsets
//       (high32) with only 2 barriers; chunk_atom map; LDS-cursor scatter;
//       zeroes deg-0 out rows.
//   K2) so3_chunk_kernel: one 64-thread wave per chunk of CEDGE=4 edges
//       (~3500 blocks -> ~3.4 waves/SIMD for latency hiding).
//       Tail slots are exact zeros (cut=0, rad=0, M=0, jsh=self).
//       B1: radial filters for 4 slots in one Wf pass, kept in REGISTERS.
//       B2: sparse-CG M[9][12] per edge in LDS (16 lanes/edge).
//       C: branch-free unrolled 4-edge contraction. nch==1 -> direct out
//       store, else plain slot store (no fences).
//   K3) so3_reduce_kernel: one wave per multi-chunk atom sums its slots.
//   Fallback (ws too small for slots): atomicAdd into zeroed out.

#define S9     9
#define MROW   12          // padded M row stride (floats)
#define NF     128
#define NRAD   20
#define CEDGE  4           // edges per chunk
#define MAXA   2048

__device__ inline float2 f2fma(float a, float2 b, float2 c) {
    return make_float2(fmaf(a, b.x, c.x), fmaf(a, b.y, c.y));
}

// ---------- K1: fused CSR build (single block, 1024 threads, A <= 2048) ----------
__global__ __launch_bounds__(1024) void csr_kernel(
    const int* __restrict__ idx_i, int E, int A, int max_chunks,
    int* __restrict__ offsets,      // [A+1]
    int* __restrict__ chunk_off,    // [A+1]
    int* __restrict__ chunk_atom,   // [max_chunks]
    int* __restrict__ esorted,      // [E]
    float* __restrict__ out)        // [A,9,128] — zero rows of deg-0 atoms
{
    __shared__ int lcnt[MAXA];
    __shared__ int lcur[MAXA];
    __shared__ unsigned long long wtot[16];
    __shared__ int nch_sh;
    const int t = threadIdx.x;
    const int lane = t & 63;
    const int wid  = t >> 6;

    for (int i = t; i < A; i += 1024) lcnt[i] = 0;
    __syncthreads();
    for (int e = t; e < E; e += 1024) atomicAdd(&lcnt[idx_i[e]], 1);
    __syncthreads();

    const int i0 = 2 * t, i1 = 2 * t + 1;
    const int ca = (i0 < A) ? lcnt[i0] : 0;
    const int cb = (i1 < A) ? lcnt[i1] : 0;
    const int ka = (i0 < A) ? ((ca + CEDGE - 1) / CEDGE) : 0;
    const int kb = (i1 < A) ? ((cb + CEDGE - 1) / CEDGE) : 0;

    // packed scan: low32 = edge counts, high32 = chunk counts (no carry across)
    const unsigned long long mine =
        (unsigned long long)(unsigned)(ca + cb) |
        ((unsigned long long)(unsigned)(ka + kb) << 32);
    unsigned long long inc = mine;
    #pragma unroll
    for (int d = 1; d < 64; d <<= 1) {
        unsigned long long u = __shfl_up(inc, d);
        if (lane >= d) inc += u;
    }
    if (lane == 63) wtot[wid] = inc;
    __syncthreads();
    if (wid == 0) {
        unsigned long long w = (lane < 16) ? wtot[lane] : 0ull;
        #pragma unroll
        for (int d = 1; d < 16; d <<= 1) {
            unsigned long long u = __shfl_up(w, d);
            if (lane >= d) w += u;
        }
        if (lane < 16) wtot[lane] = w;   // inclusive over wave totals
    }
    __syncthreads();
    const unsigned long long wpre = (wid > 0) ? wtot[wid - 1] : 0ull;
    const unsigned long long exc  = wpre + (inc - mine);   // exclusive prefix

    int run  = (int)(exc & 0xffffffffull);
    int run2 = (int)(exc >> 32);
    if (i0 < A) {
        offsets[i0] = run; lcur[i0] = run; chunk_off[i0] = run2;
        for (int k = 0; k < ka; ++k) chunk_atom[run2 + k] = i0;
        run += ca; run2 += ka;
    }
    if (i1 < A) {
        offsets[i1] = run; lcur[i1] = run; chunk_off[i1] = run2;
        for (int k = 0; k < kb; ++k) chunk_atom[run2 + k] = i1;
        run += cb; run2 += kb;
    }
    if (t == 1023) {
        const unsigned long long g = wtot[15];       // grand totals
        offsets[A]   = (int)(g & 0xffffffffull);
        chunk_off[A] = (int)(g >> 32);
        nch_sh       = (int)(g >> 32);
    }

    // zero out-rows of degree-0 atoms (rare)
    const float4 z4 = make_float4(0.f, 0.f, 0.f, 0.f);
    if (i0 < A && ca == 0) {
        float4* o = (float4*)(out + (size_t)i0 * (S9 * NF));
        for (int s = 0; s < S9 * NF / 4; ++s) o[s] = z4;
    }
    if (i1 < A && cb == 0) {
        float4* o = (float4*)(out + (size_t)i1 * (S9 * NF));
        for (int s = 0; s < S9 * NF / 4; ++s) o[s] = z4;
    }
    __syncthreads();

    // invalidate tail chunk slots (grid is max_chunks)
    for (int i = nch_sh + t; i < max_chunks; i += 1024) chunk_atom[i] = -1;

    // scatter (stable order not required)
    for (int e = t; e < E; e += 1024) {
        int p = atomicAdd(&lcur[idx_i[e]], 1);
        esorted[p] = e;
    }
}

// ---------- K2: one wave per chunk (CEDGE=4 edges) ----------
__global__ __launch_bounds__(64) void so3_chunk_kernel(
    const float* __restrict__ x,        // [A, 9, 128]
    const float* __restrict__ radial,   // [E, 20]
    const float* __restrict__ dir,      // [E, 3]
    const float* __restrict__ cutoff,   // [E]
    const float* __restrict__ Wf,       // [20, 384]
    const float* __restrict__ bf,       // [384]
    const float* __restrict__ cg_vals,
    const int* __restrict__ idx_j,
    const int* __restrict__ cg_i1,
    const int* __restrict__ cg_i2,
    const int* __restrict__ cg_i3,
    int ncg, int A,
    const int* __restrict__ offsets,    // [A+1]
    const int* __restrict__ chunk_off,  // [A+1]
    const int* __restrict__ chunk_atom, // [max_chunks]
    const int* __restrict__ esorted,    // [E]
    float* __restrict__ slots,          // [nchunks, 9, 128] (or unused)
    float* __restrict__ out,            // [A, 9, 128]
    int use_slots)
{
    const int ch = blockIdx.x;
    const int a = chunk_atom[ch];
    if (a < 0) return;

    const int c0ch = chunk_off[a];
    const int nch  = chunk_off[a + 1] - c0ch;
    const int estart = offsets[a] + (ch - c0ch) * CEDGE;
    const int n = min(CEDGE, offsets[a + 1] - estart);

    const int t = threadIdx.x;           // f-pair index: f = 2t, 2t+1

    __shared__ __align__(16) float M[CEDGE][MROW * S9];
    __shared__ float Ysh[CEDGE][S9];
    __shared__ float radsh[CEDGE][NRAD];
    __shared__ float cutsh[CEDGE];
    __shared__ int   jsh[CEDGE];

    // ---- phase A: zero M, per-slot metadata, SH, stage radial ----
    {
        float4* Mz = (float4*)&M[0][0];
        const int tot4 = CEDGE * MROW * S9 / 4;   // 108
        for (int qq = t; qq < tot4; qq += 64) Mz[qq] = make_float4(0.f, 0.f, 0.f, 0.f);
    }
    if (t < CEDGE) {
        int jj = a;              // tail slots: any valid row (contribution is 0)
        float cut = 0.f;
        if (t < n) {
            const int e = esorted[estart + t];
            jj = idx_j[e];
            cut = cutoff[e];
            float dx = dir[3 * e], dy = dir[3 * e + 1], dz = dir[3 * e + 2];
            const float inv = rsqrtf(dx * dx + dy * dy + dz * dz);
            dx *= inv; dy *= inv; dz *= inv;
            const float s3c  = 1.7320508075688772f;
            const float s5c  = 2.2360679774997896f;
            const float s15c = 3.8729833462074170f;
            Ysh[t][0] = 1.0f;
            Ysh[t][1] = s3c * dy;
            Ysh[t][2] = s3c * dz;
            Ysh[t][3] = s3c * dx;
            Ysh[t][4] = s15c * dx * dy;
            Ysh[t][5] = s15c * dy * dz;
            Ysh[t][6] = 0.5f * s5c * (3.0f * dz * dz - 1.0f);
            Ysh[t][7] = s15c * dx * dz;
            Ysh[t][8] = 0.5f * s15c * (dx * dx - dy * dy);
        }
        jsh[t] = jj;
        cutsh[t] = cut;
    }
    for (int qq = t; qq < CEDGE * NRAD; qq += 64) {
        const int c = qq / NRAD;
        const int r = qq - c * NRAD;
        radsh[c][r] = (c < n) ? radial[(size_t)esorted[estart + c] * NRAD + r] : 0.f;
    }
    __syncthreads();

    // ---- phase B1: radial filters for ALL 4 slots in one Wf pass (registers) ----
    float2 w[CEDGE][3];
    {
        const float2 b0 = ((const float2*)(bf + 0 * NF))[t];
        const float2 b1 = ((const float2*)(bf + 1 * NF))[t];
        const float2 b2 = ((const float2*)(bf + 2 * NF))[t];
        #pragma unroll
        for (int c = 0; c < CEDGE; ++c) { w[c][0] = b0; w[c][1] = b1; w[c][2] = b2; }
        #pragma unroll 4
        for (int r = 0; r < NRAD; ++r) {
            const float2* wrow = (const float2*)(Wf + r * (3 * NF));
            const float2 w0 = wrow[t];
            const float2 w1 = wrow[t + 64];
            const float2 w2 = wrow[t + 128];
            #pragma unroll
            for (int c = 0; c < CEDGE; ++c) {
                const float rv = radsh[c][r];   // 0 for c >= n
                w[c][0] = f2fma(rv, w0, w[c][0]);
                w[c][1] = f2fma(rv, w1, w[c][1]);
                w[c][2] = f2fma(rv, w2, w[c][2]);
            }
        }
        #pragma unroll
        for (int c = 0; c < CEDGE; ++c) {
            const float cut = cutsh[c];          // 0 for c >= n -> w row = 0
            w[c][0].x *= cut; w[c][0].y *= cut;
            w[c][1].x *= cut; w[c][1].y *= cut;
            w[c][2].x *= cut; w[c][2].y *= cut;
        }
    }

    // ---- phase B2: build M for all n edges (16 threads per edge) ----
    {
        const int c = t >> 4;
        const int r = t & 15;
        if (c < n) {
            for (int kk = r; kk < ncg; kk += 16) {
                atomicAdd(&M[c][cg_i3[kk] * MROW + cg_i1[kk]], cg_vals[kk] * Ysh[c][cg_i2[kk]]);
            }
        }
    }
    __syncthreads();

    // ---- phase C: branch-free fully-unrolled 4-edge contraction ----
    float2 acc[S9];
    #pragma unroll
    for (int s = 0; s < S9; ++s) acc[s] = make_float2(0.f, 0.f);

    #pragma unroll
    for (int c = 0; c < CEDGE; ++c) {
        const int j = __builtin_amdgcn_readfirstlane(jsh[c]);

        const float2* xp = (const float2*)(x + (size_t)j * (S9 * NF)) + t;
        float2 xj[S9];
        #pragma unroll
        for (int s = 0; s < S9; ++s) xj[s] = xp[s * 64];

        #pragma unroll
        for (int s3 = 0; s3 < S9; ++s3) {
            const float4* mr = (const float4*)&M[c][s3 * MROW];
            const float4 m0 = mr[0];
            const float4 m1 = mr[1];
            const float  m8 = M[c][s3 * MROW + 8];
            float2 tsum = make_float2(0.f, 0.f);
            tsum = f2fma(m0.x, xj[0], tsum);
            tsum = f2fma(m0.y, xj[1], tsum);
            tsum = f2fma(m0.z, xj[2], tsum);
            tsum = f2fma(m0.w, xj[3], tsum);
            tsum = f2fma(m1.x, xj[4], tsum);
            tsum = f2fma(m1.y, xj[5], tsum);
            tsum = f2fma(m1.z, xj[6], tsum);
            tsum = f2fma(m1.w, xj[7], tsum);
            tsum = f2fma(m8,   xj[8], tsum);
            const float2 wl = (s3 == 0) ? w[c][0] : ((s3 < 4) ? w[c][1] : w[c][2]);
            acc[s3].x = fmaf(wl.x, tsum.x, acc[s3].x);
            acc[s3].y = fmaf(wl.y, tsum.y, acc[s3].y);
        }
    }

    // ---- epilogue: plain stores only, no fences ----
    if (!use_slots) {
        float* op = out + (size_t)a * (S9 * NF) + 2 * t;
        #pragma unroll
        for (int s = 0; s < S9; ++s) {
            atomicAdd(&op[s * NF],     acc[s].x);
            atomicAdd(&op[s * NF + 1], acc[s].y);
        }
        return;
    }

    if (nch == 1) {
        float2* op = (float2*)(out + (size_t)a * (S9 * NF)) + t;
        #pragma unroll
        for (int s = 0; s < S9; ++s) op[s * 64] = acc[s];
    } else {
        float2* sp = (float2*)(slots + (size_t)ch * (S9 * NF)) + t;
        #pragma unroll
        for (int s = 0; s < S9; ++s) sp[s * 64] = acc[s];
    }
}

// ---------- K3: one wave per multi-chunk atom sums its slots ----------
__global__ __launch_bounds__(64) void so3_reduce_kernel(
    const float* __restrict__ slots, const int* __restrict__ chunk_off,
    float* __restrict__ out)
{
    const int a = blockIdx.x;
    const int t = threadIdx.x;
    const int c0 = chunk_off[a];
    const int c1 = chunk_off[a + 1];
    if (c1 - c0 < 2) return;    // deg-0 zeroed by K1; single-chunk stored by K2

    float2 acc[S9];
    #pragma unroll
    for (int s = 0; s < S9; ++s) acc[s] = make_float2(0.f, 0.f);

    for (int ch = c0; ch < c1; ++ch) {
        const float2* sp = (const float2*)(slots + (size_t)ch * (S9 * NF)) + t;
        #pragma unroll
        for (int s = 0; s < S9; ++s) {
            float2 v = sp[s * 64];
            acc[s].x += v.x; acc[s].y += v.y;
        }
    }
    float2* op = (float2*)(out + (size_t)a * (S9 * NF)) + t;
    #pragma unroll
    for (int s = 0; s < S9; ++s) op[s * 64] = acc[s];
}

extern "C" void kernel_launch(void* const* d_in, const int* in_sizes, int n_in,
                              void* d_out, int out_size, void* d_ws, size_t ws_size,
                              hipStream_t stream) {
    const float* x       = (const float*)d_in[0];
    const float* radial  = (const float*)d_in[1];
    const float* dir     = (const float*)d_in[2];
    const float* cutoff  = (const float*)d_in[3];
    const float* Wf      = (const float*)d_in[4];
    const float* bf      = (const float*)d_in[5];
    const float* cg_vals = (const float*)d_in[6];
    const int*   idx_i   = (const int*)d_in[7];
    const int*   idx_j   = (const int*)d_in[8];
    const int*   cg_i1   = (const int*)d_in[9];
    const int*   cg_i2   = (const int*)d_in[10];
    const int*   cg_i3   = (const int*)d_in[11];
    // d_in[12] = w_idx: unused (w_idx[k] == l(cg_idx_out[k]), folded into kernel)

    const int E   = in_sizes[7];
    const int ncg = in_sizes[6];
    const int A   = in_sizes[0] / (S9 * NF);

    const int max_chunks = E / CEDGE + A;   // upper bound on total chunks

    // ws ints: offsets[A+1] | chunk_off[A+1] | chunk_atom[max_chunks] | esorted[E]
    int* offsets    = (int*)d_ws;
    int* chunk_off  = offsets + (A + 1);
    int* chunk_atom = chunk_off + (A + 1);
    int* esorted    = chunk_atom + max_chunks;
    size_t int_bytes = (size_t)(2 * A + 2 + max_chunks + E) * sizeof(int);
    size_t slots_off = (int_bytes + 255) & ~(size_t)255;

    size_t slots_bytes = (size_t)max_chunks * (S9 * NF) * sizeof(float);
    const int use_slots = (ws_size >= slots_off + slots_bytes) ? 1 : 0;
    float* slots = (float*)((char*)d_ws + slots_off);
    float* out   = (float*)d_out;

    if (!use_slots) {
        // atomic fallback needs zeroed output
        hipMemsetAsync(out, 0, (size_t)out_size * sizeof(float), stream);
    }

    csr_kernel<<<1, 1024, 0, stream>>>(idx_i, E, A, max_chunks,
                                       offsets, chunk_off, chunk_atom, esorted, out);

    so3_chunk_kernel<<<max_chunks, 64, 0, stream>>>(
        x, radial, dir, cutoff, Wf, bf, cg_vals, idx_j,
        cg_i1, cg_i2, cg_i3, ncg, A, offsets, chunk_off, chunk_atom, esorted,
        slots, out, use_slots);

    if (use_slots) {
        so3_reduce_kernel<<<A, 64, 0, stream>>>(slots, chunk_off, out);
    }
}